// Round 7
// baseline (72.781 us; speedup 1.0000x reference)
//
#include <hip/hip_runtime.h>
#include <stdint.h>

#define H 128
#define W 128
#define CIN 64
#define COUT 64
#define NB 8
#define WR 4        // pixel rows per block
#define WC 16       // pixel cols per block
#define CW 20       // staged cols per window row (WC+4)
#define PLANE 162   // slots per chunk-plane; 162 % 8 == 2 -> quarter decorrelation

typedef __attribute__((ext_vector_type(4))) float f32x4;
typedef __attribute__((ext_vector_type(2))) _Float16 f16x2;
typedef __attribute__((ext_vector_type(8))) _Float16 f16x8;
typedef __attribute__((ext_vector_type(4))) unsigned int u32x4;
typedef __attribute__((ext_vector_type(2))) unsigned int u32x2;

__device__ __forceinline__ f16x2 bch2(unsigned u) { return __builtin_bit_cast(f16x2, u); }
__device__ __forceinline__ unsigned bcu(f16x2 v) { return __builtin_bit_cast(unsigned, v); }

// ---- kernel 0: x NCHW f32 -> NHWC f16 (xt[b][h][w][c]) via LDS tile transpose
__global__ __launch_bounds__(256) void x_to_nhwc(const float* __restrict__ x,
                                                 _Float16* __restrict__ xt) {
    __shared__ _Float16 tile[W][68];
    int bh = blockIdx.x;
    int h = bh & (H - 1), b = bh >> 7;
    int t = threadIdx.x;
    #pragma unroll
    for (int i = 0; i < 8; ++i) {
        int idx = i * 256 + t;
        int c = idx >> 5;
        int w4 = (idx & 31) << 2;
        f32x4 v = *(const f32x4*)(x + (((size_t)(b * CIN + c) * H + h) * W + w4));
        #pragma unroll
        for (int j = 0; j < 4; ++j) tile[w4 + j][c] = (_Float16)v[j];
    }
    __syncthreads();
    _Float16* dst = xt + (size_t)bh * W * CIN;
    #pragma unroll
    for (int i = 0; i < 8; ++i) {
        int idx = i * 256 + t;
        int w = idx >> 4;
        int c4 = (idx & 15) << 2;
        *(uint2*)(dst + (size_t)w * CIN + c4) = *(const uint2*)&tile[w][c4];
    }
}

// ---- kernel 1: prepack weights, MFMA-lane-coalesced layout
__global__ __launch_bounds__(256) void prep_w(const float* __restrict__ wo,
                                              const float* __restrict__ wc,
                                              _Float16* __restrict__ wao2,
                                              _Float16* __restrict__ wac2) {
    int t = blockIdx.x * 256 + threadIdx.x;
    if (t < 18432) {
        int j = t & 7, l = (t >> 3) & 63, m = (t >> 9) & 1, kk = t >> 10;
        int cout = m * 16 + (l & 15);
        int cin = (kk & 1) * 32 + ((l >> 4) << 3) + j;
        wao2[t] = (cout < 18) ? (_Float16)wo[(cout * 64 + cin) * 9 + (kk >> 1)]
                              : (_Float16)0.f;
    } else if (t < 18432 + 36864) {
        int u = t - 18432;
        int j = u & 7, l = (u >> 3) & 63, m = (u >> 9) & 3, kk = u >> 11;
        int cout = m * 16 + (l & 15);
        int cin = (kk & 1) * 32 + ((l >> 4) << 3) + j;
        wac2[u] = (_Float16)wc[(cout * 64 + cin) * 9 + (kk >> 1)];
    }
}

// ---- kernel 2: fused offset-conv + coord setup + deformable conv.
// Phase A reads x from global (L2-hot, coalesced) and overlaps the LDS window
// staging; single barrier before phase C; phase C 2-deep pipelined from LDS.
__global__ __launch_bounds__(256, 4) void deform_fused(const _Float16* __restrict__ xt,
                                                       const _Float16* __restrict__ wao2,
                                                       const _Float16* __restrict__ wac2,
                                                       const float* __restrict__ bo,
                                                       const float* __restrict__ bconv,
                                                       float* __restrict__ out) {
    __shared__ u32x4   s_x[8 * PLANE];   // [chunk c/8][row*CW+col], 16B slots = 20.7 KB
    __shared__ unsigned s_aw[4][9][16];  // s00 | dxb<<9 | dyb<<10 | oow<<11 | a00<<12
    __shared__ u32x2   s_wq[4][9][16];   // {g0,g1},{g2,g3} packed f16

    int bid = blockIdx.x;
    int b = bid & 7;                      // XCD swizzle: XCD k <- batch k
    int r = bid >> 3;
    int h0 = ((r >> 3) & 31) << 2;
    int w0 = (r & 7) << 4;

    int r_lo = max(0, h0 - 2), r_hi = min(H - 1, h0 + 5);
    int c_lo = max(0, w0 - 2), c_hi = min(W - 1, w0 + WC + 1);
    int nr = r_hi - r_lo + 1, nc = c_hi - c_lo + 1;

    int t = threadIdx.x;
    int lane = t & 63, wv = t >> 6;
    int pcol = lane & 15, hq = lane >> 4;
    int h = h0 + wv;
    int wp = w0 + pcol;

    const _Float16* xb = xt + (size_t)b * H * W * CIN;

    // ---------- issue phase A x-loads from global (L2-hot, coalesced) ----------
    u32x4 xgE[9], xgO[9];
    #pragma unroll
    for (int k = 0; k < 9; ++k) {
        int yy = h + k / 3 - 1;
        int xx = wp + k % 3 - 1;
        bool valid = ((unsigned)yy < (unsigned)H) && ((unsigned)xx < (unsigned)W);
        int yc = min(max(yy, 0), H - 1);
        int xc = min(max(xx, 0), W - 1);
        const _Float16* p = xb + (size_t)(yc * W + xc) * CIN + (hq << 3);
        u32x4 v0 = *(const u32x4*)p;
        u32x4 v1 = *(const u32x4*)(p + 32);
        u32x4 z = {};
        xgE[k] = valid ? v0 : z;
        xgO[k] = valid ? v1 : z;
    }

    // ---------- stage x window into LDS chunk-planes (overlaps phase A) ----------
    {
        int cs = t >> 3, ch = t & 7;
        bool act = t < nc * 8;
        for (int rr = 0; rr < nr; ++rr) {
            if (act) {
                u32x4 v = *(const u32x4*)(xb + (size_t)((r_lo + rr) * W + c_lo + cs) * CIN + (ch << 3));
                s_x[ch * PLANE + rr * CW + cs] = v;
            }
        }
    }

    // ---------- phase A: offset conv via MFMA on global-loaded x ----------
    f32x4 ao0 = {}, ao1 = {};
    #pragma unroll
    for (int k = 0; k < 9; ++k) {
        f16x8 be  = __builtin_bit_cast(f16x8, xgE[k]);
        f16x8 bod = __builtin_bit_cast(f16x8, xgO[k]);
        const _Float16* wb = wao2 + (size_t)(4 * k) * 512 + lane * 8;
        ao0 = __builtin_amdgcn_mfma_f32_16x16x32_f16(*(const f16x8*)(wb), be, ao0, 0, 0, 0);
        ao1 = __builtin_amdgcn_mfma_f32_16x16x32_f16(*(const f16x8*)(wb + 512), be, ao1, 0, 0, 0);
        ao0 = __builtin_amdgcn_mfma_f32_16x16x32_f16(*(const f16x8*)(wb + 1024), bod, ao0, 0, 0, 0);
        ao1 = __builtin_amdgcn_mfma_f32_16x16x32_f16(*(const f16x8*)(wb + 1536), bod, ao1, 0, 0, 0);
    }

    // ---------- per-lane coordinate setup ----------
    auto setup = [&](int k, float dy, float dx) {
        float py = (float)(h + k / 3 - 1) + dy;
        float px = (float)(wp + k % 3 - 1) + dx;
        float y0f = floorf(py), x0f = floorf(px);
        float fy = py - y0f, fx = px - x0f;
        float vy0 = (y0f >= 0.f  && y0f <= 127.f) ? 1.f : 0.f;
        float vy1 = (y0f >= -1.f && y0f <= 126.f) ? 1.f : 0.f;
        float vx0 = (x0f >= 0.f  && x0f <= 127.f) ? 1.f : 0.f;
        float vx1 = (x0f >= -1.f && x0f <= 126.f) ? 1.f : 0.f;
        float g0 = (1.f - fy) * (1.f - fx) * vy0 * vx0;
        float g1 = (1.f - fy) * fx         * vy0 * vx1;
        float g2 = fy * (1.f - fx)         * vy1 * vx0;
        float g3 = fy * fx                 * vy1 * vx1;
        int y0i = (int)fminf(fmaxf(y0f, 0.f), 127.f);
        int x0i = (int)fminf(fmaxf(x0f, 0.f), 127.f);
        int y1i = (int)fminf(fmaxf(y0f + 1.f, 0.f), 127.f);
        int x1i = (int)fminf(fmaxf(x0f + 1.f, 0.f), 127.f);
        unsigned dxb = (unsigned)(x1i - x0i);
        unsigned dyb = (unsigned)(y1i - y0i);
        bool inw = (y0i >= r_lo) && (y1i <= r_hi) && (x0i >= c_lo) && (x1i <= c_hi);
        unsigned s00 = inw ? (unsigned)((y0i - r_lo) * CW + (x0i - c_lo)) : 0u;
        unsigned a00 = (unsigned)(y0i * W + x0i);
        s_aw[wv][k][pcol] = s00 | (dxb << 9) | (dyb << 10) | (inw ? 0u : (1u << 11)) | (a00 << 12);
        u32x2 wq;
        wq[0] = bcu((f16x2){(_Float16)g0, (_Float16)g1});
        wq[1] = bcu((f16x2){(_Float16)g2, (_Float16)g3});
        s_wq[wv][k][pcol] = wq;
    };
    f32x4 bo4 = *(const f32x4*)(bo + 4 * hq);
    setup(2 * hq,     ao0[0] + bo4[0], ao0[1] + bo4[1]);
    setup(2 * hq + 1, ao0[2] + bo4[2], ao0[3] + bo4[3]);
    if (hq == 0) setup(8, ao1[0] + bo[16], ao1[1] + bo[17]);
    __syncthreads();

    // ---------- phase C: deformable conv, 2-deep software pipeline ----------
    const _Float16* xh = xb + (hq << 3);
    const u32x4* se = s_x + hq * PLANE;
    const u32x4* so = s_x + (4 + hq) * PLANE;
    f32x4 acc[4] = {};

    u32x4 Eb[2][4], Ob[2][4];
    {   // prologue: issue tap 0 corner reads
        unsigned aw = s_aw[wv][0][pcol];
        unsigned s00 = aw & 511u;
        unsigned dxb = (aw >> 9) & 1u;
        unsigned dyb = (aw >> 10) & 1u;
        unsigned s01 = s00 + dxb, s10 = s00 + dyb * CW, s11 = s10 + dxb;
        Eb[0][0] = se[s00]; Eb[0][1] = se[s01]; Eb[0][2] = se[s10]; Eb[0][3] = se[s11];
        Ob[0][0] = so[s00]; Ob[0][1] = so[s01]; Ob[0][2] = so[s10]; Ob[0][3] = so[s11];
    }
    #pragma unroll
    for (int k = 0; k < 9; ++k) {
        const int cur = k & 1, nxt = cur ^ 1;
        unsigned aw = s_aw[wv][k][pcol];
        u32x2 wq = s_wq[wv][k][pcol];
        if (k < 8) {   // prefetch tap k+1 corners into the other buffer
            unsigned awn = s_aw[wv][k + 1][pcol];
            unsigned n00 = awn & 511u;
            unsigned ndx = (awn >> 9) & 1u;
            unsigned ndy = (awn >> 10) & 1u;
            unsigned n01 = n00 + ndx, n10 = n00 + ndy * CW, n11 = n10 + ndx;
            Eb[nxt][0] = se[n00]; Eb[nxt][1] = se[n01]; Eb[nxt][2] = se[n10]; Eb[nxt][3] = se[n11];
            Ob[nxt][0] = so[n00]; Ob[nxt][1] = so[n01]; Ob[nxt][2] = so[n10]; Ob[nxt][3] = so[n11];
        }
        u32x4 e00 = Eb[cur][0], e01 = Eb[cur][1], e10 = Eb[cur][2], e11 = Eb[cur][3];
        u32x4 o00 = Ob[cur][0], o01 = Ob[cur][1], o10 = Ob[cur][2], o11 = Ob[cur][3];
        if (__builtin_expect((aw & (1u << 11)) != 0u, 0)) {   // rare far-offset fallback
            unsigned dxb = (aw >> 9) & 1u;
            unsigned dyb = (aw >> 10) & 1u;
            unsigned a00 = aw >> 12;
            unsigned a01 = a00 + dxb;
            unsigned a10 = a00 + (dyb << 7);
            unsigned a11 = a10 + dxb;
            const _Float16* p00 = xh + (size_t)a00 * CIN;
            const _Float16* p01 = xh + (size_t)a01 * CIN;
            const _Float16* p10 = xh + (size_t)a10 * CIN;
            const _Float16* p11 = xh + (size_t)a11 * CIN;
            e00 = *(const u32x4*)p00; o00 = *(const u32x4*)(p00 + 32);
            e01 = *(const u32x4*)p01; o01 = *(const u32x4*)(p01 + 32);
            e10 = *(const u32x4*)p10; o10 = *(const u32x4*)(p10 + 32);
            e11 = *(const u32x4*)p11; o11 = *(const u32x4*)(p11 + 32);
        }
        f16x2 wab = bch2(wq[0]);
        f16x2 wcd = bch2(wq[1]);
        f16x2 w00d = (f16x2){wab[0], wab[0]};
        f16x2 w01d = (f16x2){wab[1], wab[1]};
        f16x2 w10d = (f16x2){wcd[0], wcd[0]};
        f16x2 w11d = (f16x2){wcd[1], wcd[1]};
        u32x4 fe, fo;
        #pragma unroll
        for (int d = 0; d < 4; ++d) {
            f16x2 ve = bch2(e00[d]) * w00d + bch2(e01[d]) * w01d
                     + bch2(e10[d]) * w10d + bch2(e11[d]) * w11d;
            f16x2 vo = bch2(o00[d]) * w00d + bch2(o01[d]) * w01d
                     + bch2(o10[d]) * w10d + bch2(o11[d]) * w11d;
            fe[d] = bcu(ve);
            fo[d] = bcu(vo);
        }
        f16x8 bfe = __builtin_bit_cast(f16x8, fe);
        f16x8 bfo = __builtin_bit_cast(f16x8, fo);
        const _Float16* ab = wac2 + (size_t)(8 * k) * 512 + lane * 8;
        #pragma unroll
        for (int m = 0; m < 4; ++m)
            acc[m] = __builtin_amdgcn_mfma_f32_16x16x32_f16(*(const f16x8*)(ab + m * 512), bfe, acc[m], 0, 0, 0);
        #pragma unroll
        for (int m = 0; m < 4; ++m)
            acc[m] = __builtin_amdgcn_mfma_f32_16x16x32_f16(*(const f16x8*)(ab + (4 + m) * 512), bfo, acc[m], 0, 0, 0);
    }

    #pragma unroll
    for (int m = 0; m < 4; ++m) {
        f32x4 bc4 = *(const f32x4*)(bconv + m * 16 + (hq << 2));
        #pragma unroll
        for (int r2 = 0; r2 < 4; ++r2) {
            int co = (m << 4) + (hq << 2) + r2;
            __builtin_nontemporal_store(acc[m][r2] + bc4[r2],
                                        &out[(((size_t)b * COUT + co) * H + h) * W + wp]);
        }
    }
}

extern "C" void kernel_launch(void* const* d_in, const int* in_sizes, int n_in,
                              void* d_out, int out_size, void* d_ws, size_t ws_size,
                              hipStream_t stream) {
    const float* x  = (const float*)d_in[0];
    const float* wo = (const float*)d_in[1];
    const float* bo = (const float*)d_in[2];
    const float* wc = (const float*)d_in[3];
    const float* bc = (const float*)d_in[4];
    float* out = (float*)d_out;

    _Float16* xt   = (_Float16*)d_ws;                                   // 16.78 MB
    _Float16* wao2 = (_Float16*)((char*)d_ws + (size_t)NB * H * W * CIN * 2);
    _Float16* wac2 = wao2 + 18432;

    x_to_nhwc<<<NB * H, 256, 0, stream>>>(x, xt);
    prep_w<<<(18432 + 36864 + 255) / 256, 256, 0, stream>>>(wo, wc, wao2, wac2);
    deform_fused<<<NB * H * W / (WR * WC), 256, 0, stream>>>(xt, wao2, wac2, bo, bc, out);
}

// Round 8
// 56.742 us; speedup vs baseline: 1.2827x; 1.2827x over previous
//
#include <hip/hip_runtime.h>
#include <stdint.h>

#define H 128
#define W 128
#define CIN 64
#define COUT 64
#define NB 8
#define WR 4        // pixel rows per block
#define WC 16       // pixel cols per block
#define CW 20       // staged cols per window row (WC+4)
#define PLANE 162   // slots per chunk-plane; 162 % 8 == 2 -> quarter decorrelation

typedef __attribute__((ext_vector_type(4))) float f32x4;
typedef __attribute__((ext_vector_type(2))) _Float16 f16x2;
typedef __attribute__((ext_vector_type(8))) _Float16 f16x8;
typedef __attribute__((ext_vector_type(4))) unsigned int u32x4;
typedef __attribute__((ext_vector_type(2))) unsigned int u32x2;

__device__ __forceinline__ f16x2 bch2(unsigned u) { return __builtin_bit_cast(f16x2, u); }
__device__ __forceinline__ unsigned bcu(f16x2 v) { return __builtin_bit_cast(unsigned, v); }

// ---- kernel 0: x NCHW f32 -> NHWC f16 (xt[b][h][w][c]) via LDS tile transpose
__global__ __launch_bounds__(256) void x_to_nhwc(const float* __restrict__ x,
                                                 _Float16* __restrict__ xt) {
    __shared__ _Float16 tile[W][68];
    int bh = blockIdx.x;
    int h = bh & (H - 1), b = bh >> 7;
    int t = threadIdx.x;
    #pragma unroll
    for (int i = 0; i < 8; ++i) {
        int idx = i * 256 + t;
        int c = idx >> 5;
        int w4 = (idx & 31) << 2;
        f32x4 v = *(const f32x4*)(x + (((size_t)(b * CIN + c) * H + h) * W + w4));
        #pragma unroll
        for (int j = 0; j < 4; ++j) tile[w4 + j][c] = (_Float16)v[j];
    }
    __syncthreads();
    _Float16* dst = xt + (size_t)bh * W * CIN;
    #pragma unroll
    for (int i = 0; i < 8; ++i) {
        int idx = i * 256 + t;
        int w = idx >> 4;
        int c4 = (idx & 15) << 2;
        *(uint2*)(dst + (size_t)w * CIN + c4) = *(const uint2*)&tile[w][c4];
    }
}

// ---- kernel 1: prepack weights, MFMA-lane-coalesced layout
__global__ __launch_bounds__(256) void prep_w(const float* __restrict__ wo,
                                              const float* __restrict__ wc,
                                              _Float16* __restrict__ wao2,
                                              _Float16* __restrict__ wac2) {
    int t = blockIdx.x * 256 + threadIdx.x;
    if (t < 18432) {
        int j = t & 7, l = (t >> 3) & 63, m = (t >> 9) & 1, kk = t >> 10;
        int cout = m * 16 + (l & 15);
        int cin = (kk & 1) * 32 + ((l >> 4) << 3) + j;
        wao2[t] = (cout < 18) ? (_Float16)wo[(cout * 64 + cin) * 9 + (kk >> 1)]
                              : (_Float16)0.f;
    } else if (t < 18432 + 36864) {
        int u = t - 18432;
        int j = u & 7, l = (u >> 3) & 63, m = (u >> 9) & 3, kk = u >> 11;
        int cout = m * 16 + (l & 15);
        int cin = (kk & 1) * 32 + ((l >> 4) << 3) + j;
        wac2[u] = (_Float16)wc[(cout * 64 + cin) * 9 + (kk >> 1)];
    }
}

// ---- kernel 2: fused offset-conv + coord setup + deformable conv.
// Phase C: per-tap metadata preloaded to registers; corner reads double-
// buffered and PINNED with empty asm so the compiler cannot sink them.
__global__ __launch_bounds__(256, 4) void deform_fused(const _Float16* __restrict__ xt,
                                                       const _Float16* __restrict__ wao2,
                                                       const _Float16* __restrict__ wac2,
                                                       const float* __restrict__ bo,
                                                       const float* __restrict__ bconv,
                                                       float* __restrict__ out) {
    __shared__ u32x4   s_x[8 * PLANE];   // [chunk c/8][row*CW+col], 16B slots = 20.7 KB
    __shared__ unsigned s_aw[4][9][16];  // s00 | dxb<<9 | dyb<<10 | oow<<11 | a00<<12
    __shared__ u32x2   s_wq[4][9][16];   // {g0,g1},{g2,g3} packed f16

    int bid = blockIdx.x;
    int b = bid & 7;                      // XCD swizzle: XCD k <- batch k
    int r = bid >> 3;
    int h0 = ((r >> 3) & 31) << 2;
    int w0 = (r & 7) << 4;

    int r_lo = max(0, h0 - 2), r_hi = min(H - 1, h0 + 5);
    int c_lo = max(0, w0 - 2), c_hi = min(W - 1, w0 + WC + 1);
    int nr = r_hi - r_lo + 1, nc = c_hi - c_lo + 1;

    int t = threadIdx.x;
    int lane = t & 63, wv = t >> 6;
    int pcol = lane & 15, hq = lane >> 4;
    int h = h0 + wv;
    int wp = w0 + pcol;

    const _Float16* xb = xt + (size_t)b * H * W * CIN;

    // ---------- stage x window into LDS chunk-planes ----------
    {
        int cs = t >> 3, ch = t & 7;
        bool act = t < nc * 8;
        for (int rr = 0; rr < nr; ++rr) {
            if (act) {
                u32x4 v = *(const u32x4*)(xb + (size_t)((r_lo + rr) * W + c_lo + cs) * CIN + (ch << 3));
                s_x[ch * PLANE + rr * CW + cs] = v;
            }
        }
    }
    __syncthreads();

    // ---------- phase A: offset conv via MFMA, x from LDS ----------
    f32x4 ao0 = {}, ao1 = {};
    #pragma unroll
    for (int k = 0; k < 9; ++k) {
        int yy = h + k / 3 - 1;
        int xx = wp + k % 3 - 1;
        bool valid = ((unsigned)yy < (unsigned)H) && ((unsigned)xx < (unsigned)W);
        int yc = min(max(yy, 0), H - 1);
        int xc = min(max(xx, 0), W - 1);
        int s = (yc - r_lo) * CW + (xc - c_lo);
        u32x4 ve = s_x[hq * PLANE + s];
        u32x4 vo = s_x[(4 + hq) * PLANE + s];
        u32x4 z = {};
        if (!valid) { ve = z; vo = z; }
        f16x8 be = __builtin_bit_cast(f16x8, ve);
        f16x8 bod = __builtin_bit_cast(f16x8, vo);
        const _Float16* wb = wao2 + (size_t)(4 * k) * 512 + lane * 8;
        ao0 = __builtin_amdgcn_mfma_f32_16x16x32_f16(*(const f16x8*)(wb), be, ao0, 0, 0, 0);
        ao1 = __builtin_amdgcn_mfma_f32_16x16x32_f16(*(const f16x8*)(wb + 512), be, ao1, 0, 0, 0);
        ao0 = __builtin_amdgcn_mfma_f32_16x16x32_f16(*(const f16x8*)(wb + 1024), bod, ao0, 0, 0, 0);
        ao1 = __builtin_amdgcn_mfma_f32_16x16x32_f16(*(const f16x8*)(wb + 1536), bod, ao1, 0, 0, 0);
    }

    // ---------- per-lane coordinate setup ----------
    auto setup = [&](int k, float dy, float dx) {
        float py = (float)(h + k / 3 - 1) + dy;
        float px = (float)(wp + k % 3 - 1) + dx;
        float y0f = floorf(py), x0f = floorf(px);
        float fy = py - y0f, fx = px - x0f;
        float vy0 = (y0f >= 0.f  && y0f <= 127.f) ? 1.f : 0.f;
        float vy1 = (y0f >= -1.f && y0f <= 126.f) ? 1.f : 0.f;
        float vx0 = (x0f >= 0.f  && x0f <= 127.f) ? 1.f : 0.f;
        float vx1 = (x0f >= -1.f && x0f <= 126.f) ? 1.f : 0.f;
        float g0 = (1.f - fy) * (1.f - fx) * vy0 * vx0;
        float g1 = (1.f - fy) * fx         * vy0 * vx1;
        float g2 = fy * (1.f - fx)         * vy1 * vx0;
        float g3 = fy * fx                 * vy1 * vx1;
        int y0i = (int)fminf(fmaxf(y0f, 0.f), 127.f);
        int x0i = (int)fminf(fmaxf(x0f, 0.f), 127.f);
        int y1i = (int)fminf(fmaxf(y0f + 1.f, 0.f), 127.f);
        int x1i = (int)fminf(fmaxf(x0f + 1.f, 0.f), 127.f);
        unsigned dxb = (unsigned)(x1i - x0i);
        unsigned dyb = (unsigned)(y1i - y0i);
        bool inw = (y0i >= r_lo) && (y1i <= r_hi) && (x0i >= c_lo) && (x1i <= c_hi);
        unsigned s00 = inw ? (unsigned)((y0i - r_lo) * CW + (x0i - c_lo)) : 0u;
        unsigned a00 = (unsigned)(y0i * W + x0i);
        s_aw[wv][k][pcol] = s00 | (dxb << 9) | (dyb << 10) | (inw ? 0u : (1u << 11)) | (a00 << 12);
        u32x2 wq;
        wq[0] = bcu((f16x2){(_Float16)g0, (_Float16)g1});
        wq[1] = bcu((f16x2){(_Float16)g2, (_Float16)g3});
        s_wq[wv][k][pcol] = wq;
    };
    f32x4 bo4 = *(const f32x4*)(bo + 4 * hq);
    setup(2 * hq,     ao0[0] + bo4[0], ao0[1] + bo4[1]);
    setup(2 * hq + 1, ao0[2] + bo4[2], ao0[3] + bo4[3]);
    if (hq == 0) setup(8, ao1[0] + bo[16], ao1[1] + bo[17]);
    __syncthreads();

    // ---------- phase C: deformable conv, forced 2-deep pipeline ----------
    const _Float16* xh = xb + (hq << 3);
    const u32x4* se = s_x + hq * PLANE;
    const u32x4* so = s_x + (4 + hq) * PLANE;
    f32x4 acc[4] = {};

    // preload all per-tap metadata into registers (breaks in-loop LDS deps)
    unsigned AW[9];
    u32x2   WQ[9];
    #pragma unroll
    for (int k = 0; k < 9; ++k) {
        AW[k] = s_aw[wv][k][pcol];
        WQ[k] = s_wq[wv][k][pcol];
    }

    u32x4 E[2][4], O[2][4];
    #define FETCH(kk, buf)                                                    \
        {                                                                     \
            unsigned aw_ = AW[kk];                                            \
            unsigned s00_ = aw_ & 511u;                                       \
            unsigned dx_ = (aw_ >> 9) & 1u;                                   \
            unsigned dy_ = (aw_ >> 10) & 1u;                                  \
            unsigned s01_ = s00_ + dx_, s10_ = s00_ + dy_ * CW, s11_ = s10_ + dx_; \
            E[buf][0] = se[s00_]; E[buf][1] = se[s01_];                       \
            E[buf][2] = se[s10_]; E[buf][3] = se[s11_];                       \
            O[buf][0] = so[s00_]; O[buf][1] = so[s01_];                       \
            O[buf][2] = so[s10_]; O[buf][3] = so[s11_];                       \
            asm volatile("" : "+v"(E[buf][0]), "+v"(E[buf][1]),               \
                              "+v"(E[buf][2]), "+v"(E[buf][3]),               \
                              "+v"(O[buf][0]), "+v"(O[buf][1]),               \
                              "+v"(O[buf][2]), "+v"(O[buf][3]));              \
        }

    FETCH(0, 0);
    #pragma unroll
    for (int k = 0; k < 9; ++k) {
        const int cur = k & 1, nxt = cur ^ 1;
        if (k < 8) FETCH(k + 1, nxt);
        unsigned aw = AW[k];
        u32x2 wq = WQ[k];
        u32x4 e00 = E[cur][0], e01 = E[cur][1], e10 = E[cur][2], e11 = E[cur][3];
        u32x4 o00 = O[cur][0], o01 = O[cur][1], o10 = O[cur][2], o11 = O[cur][3];
        if (__builtin_expect((aw & (1u << 11)) != 0u, 0)) {   // rare far-offset fallback
            unsigned dxb = (aw >> 9) & 1u;
            unsigned dyb = (aw >> 10) & 1u;
            unsigned a00 = aw >> 12;
            unsigned a01 = a00 + dxb;
            unsigned a10 = a00 + (dyb << 7);
            unsigned a11 = a10 + dxb;
            const _Float16* p00 = xh + (size_t)a00 * CIN;
            const _Float16* p01 = xh + (size_t)a01 * CIN;
            const _Float16* p10 = xh + (size_t)a10 * CIN;
            const _Float16* p11 = xh + (size_t)a11 * CIN;
            e00 = *(const u32x4*)p00; o00 = *(const u32x4*)(p00 + 32);
            e01 = *(const u32x4*)p01; o01 = *(const u32x4*)(p01 + 32);
            e10 = *(const u32x4*)p10; o10 = *(const u32x4*)(p10 + 32);
            e11 = *(const u32x4*)p11; o11 = *(const u32x4*)(p11 + 32);
        }
        f16x2 wab = bch2(wq[0]);
        f16x2 wcd = bch2(wq[1]);
        f16x2 w00d = (f16x2){wab[0], wab[0]};
        f16x2 w01d = (f16x2){wab[1], wab[1]};
        f16x2 w10d = (f16x2){wcd[0], wcd[0]};
        f16x2 w11d = (f16x2){wcd[1], wcd[1]};
        u32x4 fe, fo;
        #pragma unroll
        for (int d = 0; d < 4; ++d) {
            f16x2 ve = bch2(e00[d]) * w00d + bch2(e01[d]) * w01d
                     + bch2(e10[d]) * w10d + bch2(e11[d]) * w11d;
            f16x2 vo = bch2(o00[d]) * w00d + bch2(o01[d]) * w01d
                     + bch2(o10[d]) * w10d + bch2(o11[d]) * w11d;
            fe[d] = bcu(ve);
            fo[d] = bcu(vo);
        }
        f16x8 bfe = __builtin_bit_cast(f16x8, fe);
        f16x8 bfo = __builtin_bit_cast(f16x8, fo);
        const _Float16* ab = wac2 + (size_t)(8 * k) * 512 + lane * 8;
        #pragma unroll
        for (int m = 0; m < 4; ++m)
            acc[m] = __builtin_amdgcn_mfma_f32_16x16x32_f16(*(const f16x8*)(ab + m * 512), bfe, acc[m], 0, 0, 0);
        #pragma unroll
        for (int m = 0; m < 4; ++m)
            acc[m] = __builtin_amdgcn_mfma_f32_16x16x32_f16(*(const f16x8*)(ab + (4 + m) * 512), bfo, acc[m], 0, 0, 0);
    }
    #undef FETCH

    #pragma unroll
    for (int m = 0; m < 4; ++m) {
        f32x4 bc4 = *(const f32x4*)(bconv + m * 16 + (hq << 2));
        #pragma unroll
        for (int r2 = 0; r2 < 4; ++r2) {
            int co = (m << 4) + (hq << 2) + r2;
            out[(((size_t)b * COUT + co) * H + h) * W + wp] = acc[m][r2] + bc4[r2];
        }
    }
}

extern "C" void kernel_launch(void* const* d_in, const int* in_sizes, int n_in,
                              void* d_out, int out_size, void* d_ws, size_t ws_size,
                              hipStream_t stream) {
    const float* x  = (const float*)d_in[0];
    const float* wo = (const float*)d_in[1];
    const float* bo = (const float*)d_in[2];
    const float* wc = (const float*)d_in[3];
    const float* bc = (const float*)d_in[4];
    float* out = (float*)d_out;

    _Float16* xt   = (_Float16*)d_ws;                                   // 16.78 MB
    _Float16* wao2 = (_Float16*)((char*)d_ws + (size_t)NB * H * W * CIN * 2);
    _Float16* wac2 = wao2 + 18432;

    x_to_nhwc<<<NB * H, 256, 0, stream>>>(x, xt);
    prep_w<<<(18432 + 36864 + 255) / 256, 256, 0, stream>>>(wo, wc, wao2, wac2);
    deform_fused<<<NB * H * W / (WR * WC), 256, 0, stream>>>(xt, wao2, wac2, bo, bc, out);
}

// Round 9
// 54.738 us; speedup vs baseline: 1.3296x; 1.0366x over previous
//
#include <hip/hip_runtime.h>
#include <stdint.h>

#define H 128
#define W 128
#define CIN 64
#define COUT 64
#define NB 8
#define WR 4        // pixel rows per block
#define WC 16       // pixel cols per block
#define CW 20       // staged cols per window row (WC+4)
#define PLANE 162   // slots per chunk-plane; 162 % 8 == 2 -> quarter decorrelation
#define REDS 260    // reduction scratch row stride (floats)

typedef __attribute__((ext_vector_type(4))) float f32x4;
typedef __attribute__((ext_vector_type(2))) _Float16 f16x2;
typedef __attribute__((ext_vector_type(8))) _Float16 f16x8;
typedef __attribute__((ext_vector_type(4))) unsigned int u32x4;
typedef __attribute__((ext_vector_type(2))) unsigned int u32x2;

__device__ __forceinline__ f16x2 bch2(unsigned u) { return __builtin_bit_cast(f16x2, u); }
__device__ __forceinline__ unsigned bcu(f16x2 v) { return __builtin_bit_cast(unsigned, v); }

// ---- kernel 0: x NCHW f32 -> NHWC f16 (xt[b][h][w][c]) via LDS tile transpose
__global__ __launch_bounds__(256) void x_to_nhwc(const float* __restrict__ x,
                                                 _Float16* __restrict__ xt) {
    __shared__ _Float16 tile[W][68];
    int bh = blockIdx.x;
    int h = bh & (H - 1), b = bh >> 7;
    int t = threadIdx.x;
    #pragma unroll
    for (int i = 0; i < 8; ++i) {
        int idx = i * 256 + t;
        int c = idx >> 5;
        int w4 = (idx & 31) << 2;
        f32x4 v = *(const f32x4*)(x + (((size_t)(b * CIN + c) * H + h) * W + w4));
        #pragma unroll
        for (int j = 0; j < 4; ++j) tile[w4 + j][c] = (_Float16)v[j];
    }
    __syncthreads();
    _Float16* dst = xt + (size_t)bh * W * CIN;
    #pragma unroll
    for (int i = 0; i < 8; ++i) {
        int idx = i * 256 + t;
        int w = idx >> 4;
        int c4 = (idx & 15) << 2;
        *(uint2*)(dst + (size_t)w * CIN + c4) = *(const uint2*)&tile[w][c4];
    }
}

// ---- kernel 1: prepack weights, MFMA-lane-coalesced layout
//  wao2[((kk*2+m)*64 + l)*8 + j] ; wac2[((kk*4+m)*64 + l)*8 + j]
//  element = w[cout = m*16+(l&15)][cin = (kk&1)*32 + (l>>4)*8 + j][tap = kk>>1]
__global__ __launch_bounds__(256) void prep_w(const float* __restrict__ wo,
                                              const float* __restrict__ wc,
                                              _Float16* __restrict__ wao2,
                                              _Float16* __restrict__ wac2) {
    int t = blockIdx.x * 256 + threadIdx.x;
    if (t < 18432) {
        int j = t & 7, l = (t >> 3) & 63, m = (t >> 9) & 1, kk = t >> 10;
        int cout = m * 16 + (l & 15);
        int cin = (kk & 1) * 32 + ((l >> 4) << 3) + j;
        wao2[t] = (cout < 18) ? (_Float16)wo[(cout * 64 + cin) * 9 + (kk >> 1)]
                              : (_Float16)0.f;
    } else if (t < 18432 + 36864) {
        int u = t - 18432;
        int j = u & 7, l = (u >> 3) & 63, m = (u >> 9) & 3, kk = u >> 11;
        int cout = m * 16 + (l & 15);
        int cin = (kk & 1) * 32 + ((l >> 4) << 3) + j;
        wac2[u] = (_Float16)wc[(cout * 64 + cin) * 9 + (kk >> 1)];
    }
}

// ---- kernel 2: fused offset-conv + coord setup + deformable conv.
// 512 threads = 8 waves. Wave-pair K-split: waves 0-3 = channels 0..31,
// waves 4-7 = channels 32..63, same 4x16 pixel tile; partial sums reduced
// through LDS. Halves each wave's serial chain, doubles wave-level parallelism.
__global__ __launch_bounds__(512, 5) void deform_fused(const _Float16* __restrict__ xt,
                                                       const _Float16* __restrict__ wao2,
                                                       const _Float16* __restrict__ wac2,
                                                       const float* __restrict__ bo,
                                                       const float* __restrict__ bconv,
                                                       float* __restrict__ out) {
    __shared__ u32x4 s_x[8 * PLANE];     // [chunk c/8][row*CW+col], 16B slots = 20.7 KB
    __shared__ float s_meta[4][432];     // per pixel-row g: aw[144] | wq pairs[288]
                                         // (also aliased as phase-A partial scratch)

    int bid = blockIdx.x;
    int b = bid & 7;                      // XCD swizzle: XCD k <- batch k
    int r = bid >> 3;
    int h0 = ((r >> 3) & 31) << 2;
    int w0 = (r & 7) << 4;

    int r_lo = max(0, h0 - 2), r_hi = min(H - 1, h0 + 5);
    int c_lo = max(0, w0 - 2), c_hi = min(W - 1, w0 + WC + 1);
    int nr = r_hi - r_lo + 1, nc = c_hi - c_lo + 1;

    int t = threadIdx.x;
    int lane = t & 63, wv = t >> 6;
    int g = wv & 3;                       // pixel row within tile
    int half = wv >> 2;                   // 0: ch 0..31, 1: ch 32..63
    int pcol = lane & 15, hq = lane >> 4;
    int pl = half * 4 + hq;               // this lane's channel chunk (8 ch)
    int h = h0 + g;
    int wp = w0 + pcol;

    const _Float16* xb = xt + (size_t)b * H * W * CIN;

    // ---------- stage x window into LDS chunk-planes ----------
    {
        int cs = t >> 3, ch = t & 7;
        bool act = t < nc * 8;
        for (int rr = 0; rr < nr; ++rr) {
            if (act) {
                u32x4 v = *(const u32x4*)(xb + (size_t)((r_lo + rr) * W + c_lo + cs) * CIN + (ch << 3));
                s_x[ch * PLANE + rr * CW + cs] = v;
            }
        }
    }
    __syncthreads();

    const u32x4* sp = s_x + pl * PLANE;

    // ---------- phase A: offset conv via MFMA (this wave's channel half) ----------
    f32x4 ao0 = {}, ao1 = {};
    #pragma unroll
    for (int k = 0; k < 9; ++k) {
        int yy = h + k / 3 - 1;
        int xx = wp + k % 3 - 1;
        bool valid = ((unsigned)yy < (unsigned)H) && ((unsigned)xx < (unsigned)W);
        int yc = min(max(yy, 0), H - 1);
        int xc = min(max(xx, 0), W - 1);
        int s = (yc - r_lo) * CW + (xc - c_lo);
        u32x4 v = sp[s];
        u32x4 z = {};
        if (!valid) v = z;
        f16x8 bf = __builtin_bit_cast(f16x8, v);
        const _Float16* wb = wao2 + (size_t)(4 * k + 2 * half) * 512 + lane * 8;
        ao0 = __builtin_amdgcn_mfma_f32_16x16x32_f16(*(const f16x8*)(wb), bf, ao0, 0, 0, 0);
        ao1 = __builtin_amdgcn_mfma_f32_16x16x32_f16(*(const f16x8*)(wb + 512), bf, ao1, 0, 0, 0);
    }

    // ---------- reduce phase-A partials (odd half -> LDS -> even half) ----------
    if (half == 1) {
        float* sc = s_meta[g] + lane * 6;
        sc[0] = ao0[0]; sc[1] = ao0[1]; sc[2] = ao0[2]; sc[3] = ao0[3];
        sc[4] = ao1[0]; sc[5] = ao1[1];
    }
    __syncthreads();

    if (half == 0) {
        // read partner's partials FIRST (wave-lockstep makes the later aliased
        // metadata writes safe: all reads issue before any write)
        const float* sc = s_meta[g] + lane * 6;
        float p0 = sc[0], p1 = sc[1], p2 = sc[2], p3 = sc[3], p4 = sc[4], p5 = sc[5];
        ao0[0] += p0; ao0[1] += p1; ao0[2] += p2; ao0[3] += p3;
        ao1[0] += p4; ao1[1] += p5;

        auto setup = [&](int k, float dy, float dx) {
            float py = (float)(h + k / 3 - 1) + dy;
            float px = (float)(wp + k % 3 - 1) + dx;
            float y0f = floorf(py), x0f = floorf(px);
            float fy = py - y0f, fx = px - x0f;
            float vy0 = (y0f >= 0.f  && y0f <= 127.f) ? 1.f : 0.f;
            float vy1 = (y0f >= -1.f && y0f <= 126.f) ? 1.f : 0.f;
            float vx0 = (x0f >= 0.f  && x0f <= 127.f) ? 1.f : 0.f;
            float vx1 = (x0f >= -1.f && x0f <= 126.f) ? 1.f : 0.f;
            float g0 = (1.f - fy) * (1.f - fx) * vy0 * vx0;
            float g1 = (1.f - fy) * fx         * vy0 * vx1;
            float g2 = fy * (1.f - fx)         * vy1 * vx0;
            float g3 = fy * fx                 * vy1 * vx1;
            int y0i = (int)fminf(fmaxf(y0f, 0.f), 127.f);
            int x0i = (int)fminf(fmaxf(x0f, 0.f), 127.f);
            int y1i = (int)fminf(fmaxf(y0f + 1.f, 0.f), 127.f);
            int x1i = (int)fminf(fmaxf(x0f + 1.f, 0.f), 127.f);
            unsigned dxb = (unsigned)(x1i - x0i);
            unsigned dyb = (unsigned)(y1i - y0i);
            bool inw = (y0i >= r_lo) && (y1i <= r_hi) && (x0i >= c_lo) && (x1i <= c_hi);
            unsigned s00 = inw ? (unsigned)((y0i - r_lo) * CW + (x0i - c_lo)) : 0u;
            unsigned a00 = (unsigned)(y0i * W + x0i);
            unsigned awv = s00 | (dxb << 9) | (dyb << 10) | (inw ? 0u : (1u << 11)) | (a00 << 12);
            int idx = k * 16 + pcol;
            ((unsigned*)s_meta[g])[idx] = awv;
            ((unsigned*)s_meta[g])[144 + 2 * idx]     = bcu((f16x2){(_Float16)g0, (_Float16)g1});
            ((unsigned*)s_meta[g])[144 + 2 * idx + 1] = bcu((f16x2){(_Float16)g2, (_Float16)g3});
        };
        f32x4 bo4 = *(const f32x4*)(bo + 4 * hq);
        setup(2 * hq,     ao0[0] + bo4[0], ao0[1] + bo4[1]);
        setup(2 * hq + 1, ao0[2] + bo4[2], ao0[3] + bo4[3]);
        if (hq == 0) setup(8, ao1[0] + bo[16], ao1[1] + bo[17]);
    }
    __syncthreads();

    // ---------- phase C: deformable conv (this wave's channel half) ----------
    const _Float16* xh = xb + (pl << 3);
    f32x4 acc[4] = {};

    unsigned AW[9];
    #pragma unroll
    for (int k = 0; k < 9; ++k) AW[k] = ((unsigned*)s_meta[g])[k * 16 + pcol];

    u32x4 C0[4], C1[4];
    #define FETCH(kk, Cb)                                                      \
        {                                                                      \
            unsigned aw_ = AW[kk];                                             \
            unsigned s00_ = aw_ & 511u;                                        \
            unsigned dx_ = (aw_ >> 9) & 1u;                                    \
            unsigned dy_ = (aw_ >> 10) & 1u;                                   \
            unsigned s01_ = s00_ + dx_, s10_ = s00_ + dy_ * CW, s11_ = s10_ + dx_; \
            Cb[0] = sp[s00_]; Cb[1] = sp[s01_];                                \
            Cb[2] = sp[s10_]; Cb[3] = sp[s11_];                                \
        }

    FETCH(0, C0);
    #pragma unroll
    for (int k = 0; k < 9; ++k) {
        u32x4 c00, c01, c10, c11;
        if (k & 1) { c00 = C1[0]; c01 = C1[1]; c10 = C1[2]; c11 = C1[3]; }
        else       { c00 = C0[0]; c01 = C0[1]; c10 = C0[2]; c11 = C0[3]; }
        if (k < 8) {
            if (k & 1) { FETCH(k + 1, C0) }
            else       { FETCH(k + 1, C1) }
        }
        unsigned aw = AW[k];
        u32x2 wq = *(const u32x2*)&((unsigned*)s_meta[g])[144 + 2 * (k * 16 + pcol)];
        if (__builtin_expect((aw & (1u << 11)) != 0u, 0)) {   // rare far-offset fallback
            unsigned dxb = (aw >> 9) & 1u;
            unsigned dyb = (aw >> 10) & 1u;
            unsigned a00 = aw >> 12;
            unsigned a01 = a00 + dxb;
            unsigned a10 = a00 + (dyb << 7);
            unsigned a11 = a10 + dxb;
            c00 = *(const u32x4*)(xh + (size_t)a00 * CIN);
            c01 = *(const u32x4*)(xh + (size_t)a01 * CIN);
            c10 = *(const u32x4*)(xh + (size_t)a10 * CIN);
            c11 = *(const u32x4*)(xh + (size_t)a11 * CIN);
        }
        f16x2 wab = bch2(wq[0]);
        f16x2 wcd = bch2(wq[1]);
        f16x2 w00d = (f16x2){wab[0], wab[0]};
        f16x2 w01d = (f16x2){wab[1], wab[1]};
        f16x2 w10d = (f16x2){wcd[0], wcd[0]};
        f16x2 w11d = (f16x2){wcd[1], wcd[1]};
        u32x4 fr;
        #pragma unroll
        for (int d = 0; d < 4; ++d) {
            f16x2 v = bch2(c00[d]) * w00d + bch2(c01[d]) * w01d
                    + bch2(c10[d]) * w10d + bch2(c11[d]) * w11d;
            fr[d] = bcu(v);
        }
        f16x8 bf = __builtin_bit_cast(f16x8, fr);
        const _Float16* ab = wac2 + (size_t)(8 * k + 4 * half) * 512 + lane * 8;
        #pragma unroll
        for (int m = 0; m < 4; ++m)
            acc[m] = __builtin_amdgcn_mfma_f32_16x16x32_f16(*(const f16x8*)(ab + m * 512), bf, acc[m], 0, 0, 0);
    }
    #undef FETCH

    // ---------- reduce phase-C partials through s_x (dead now) ----------
    __syncthreads();                      // all s_x corner reads complete
    float* red = (float*)s_x;             // [16][REDS] transposed: conflict-free b32
    if (half == 0) {
        #pragma unroll
        for (int m = 0; m < 4; ++m)
            #pragma unroll
            for (int r2 = 0; r2 < 4; ++r2)
                red[(m * 4 + r2) * REDS + g * 64 + lane] = acc[m][r2];
    }
    __syncthreads();
    if (half == 1) {
        #pragma unroll
        for (int m = 0; m < 4; ++m) {
            f32x4 bc4 = *(const f32x4*)(bconv + m * 16 + (hq << 2));
            #pragma unroll
            for (int r2 = 0; r2 < 4; ++r2) {
                int co = (m << 4) + (hq << 2) + r2;
                float v = acc[m][r2] + red[(m * 4 + r2) * REDS + g * 64 + lane] + bc4[r2];
                out[(((size_t)b * COUT + co) * H + h) * W + wp] = v;
            }
        }
    }
}

extern "C" void kernel_launch(void* const* d_in, const int* in_sizes, int n_in,
                              void* d_out, int out_size, void* d_ws, size_t ws_size,
                              hipStream_t stream) {
    const float* x  = (const float*)d_in[0];
    const float* wo = (const float*)d_in[1];
    const float* bo = (const float*)d_in[2];
    const float* wc = (const float*)d_in[3];
    const float* bc = (const float*)d_in[4];
    float* out = (float*)d_out;

    _Float16* xt   = (_Float16*)d_ws;                                   // 16.78 MB
    _Float16* wao2 = (_Float16*)((char*)d_ws + (size_t)NB * H * W * CIN * 2);
    _Float16* wac2 = wao2 + 18432;

    x_to_nhwc<<<NB * H, 256, 0, stream>>>(x, xt);
    prep_w<<<(18432 + 36864 + 255) / 256, 256, 0, stream>>>(wo, wc, wao2, wac2);
    deform_fused<<<NB * H * W / (WR * WC), 512, 0, stream>>>(xt, wao2, wac2, bo, bc, out);
}